// Round 8
// baseline (423.204 us; speedup 1.0000x reference)
//
#include <hip/hip_runtime.h>

// ---------------------------------------------------------------------------
// MultiHeadAttention forward: B=2, S=2048, D=1024, H=16, depth=64
// d_out (f32): out [B,S,D] (4,194,304) ++ attn [B,H,S,S] (134,217,728)
// d_ws: q, k, vT, ctx bf16 = 4 x 8 MiB = 32 MiB.
// bf16 copies of x,wq,wk,wv live transiently in the attn output region.
// ---------------------------------------------------------------------------

#define S_LEN 2048
#define D_DIM 1024
#define H_NUM 16
#define M_ROWS 4096   // B*S

typedef __attribute__((ext_vector_type(8))) short bf16x8;
typedef __attribute__((ext_vector_type(4))) float f32x4;

static __device__ __forceinline__ unsigned short f2bf(float f) {
  union { float f; unsigned u; } v; v.f = f;
  unsigned r = (v.u + 0x7FFFu + ((v.u >> 16) & 1u)) >> 16;  // RNE
  return (unsigned short)r;
}

static __device__ __forceinline__ bf16x8 cvt8(float4 a, float4 b) {
  bf16x8 r;
  r[0] = (short)f2bf(a.x); r[1] = (short)f2bf(a.y);
  r[2] = (short)f2bf(a.z); r[3] = (short)f2bf(a.w);
  r[4] = (short)f2bf(b.x); r[5] = (short)f2bf(b.y);
  r[6] = (short)f2bf(b.z); r[7] = (short)f2bf(b.w);
  return r;
}

static __device__ __forceinline__ void gld16(const void* g, void* s) {
  __builtin_amdgcn_global_load_lds(
      (const __attribute__((address_space(1))) unsigned int*)g,
      (__attribute__((address_space(3))) unsigned int*)s, 16, 0, 0);
}

// ---------------------------------------------------------------------------
__global__ __launch_bounds__(256) void cast_f32_bf16(
    const float* __restrict__ src, unsigned short* __restrict__ dst, int n4) {
  int i = blockIdx.x * 256 + threadIdx.x;
  if (i >= n4) return;
  float4 v = ((const float4*)src)[i];
  unsigned long long o =
      (unsigned long long)f2bf(v.x) |
      ((unsigned long long)f2bf(v.y) << 16) |
      ((unsigned long long)f2bf(v.z) << 32) |
      ((unsigned long long)f2bf(v.w) << 48);
  ((unsigned long long*)dst)[i] = o;
}

// ---------------------------------------------------------------------------
// m97-structure GEMM: C bf16 = A @ W^T + bias.  blockIdx.z selects q/k/v.
// z==2 (V) writes the result TRANSPOSED per head: vT[b][h][d][s].
// (unchanged, R6/R7-verified)
// ---------------------------------------------------------------------------
__global__ __launch_bounds__(256) void gemm_qkv(
    const unsigned short* __restrict__ A,
    const unsigned short* __restrict__ W0, const unsigned short* __restrict__ W1,
    const unsigned short* __restrict__ W2,
    const float* __restrict__ b0, const float* __restrict__ b1,
    const float* __restrict__ b2,
    unsigned short* __restrict__ C0, unsigned short* __restrict__ C1,
    unsigned short* __restrict__ C2) {
  const unsigned short* W = W0; const float* bias = b0; unsigned short* C = C0;
  if (blockIdx.z == 1) { W = W1; bias = b1; C = C1; }
  else if (blockIdx.z == 2) { W = W2; bias = b2; C = C2; }

  __shared__ __align__(16) unsigned short As[128 * 64];
  __shared__ __align__(16) unsigned short Bs[128 * 64];

  const int tid = threadIdx.x;
  const int l = tid & 63;
  const int w = tid >> 6;
  const int wm = w >> 1, wn = w & 1;
  const int lo = l & 15, hi = l >> 4;

  const int mBase = blockIdx.y * 128;
  const int nBase = blockIdx.x * 128;

  f32x4 acc[4][4];
  for (int mr = 0; mr < 4; ++mr)
    for (int nr = 0; nr < 4; ++nr) acc[mr][nr] = (f32x4){0.f, 0.f, 0.f, 0.f};

  for (int k0 = 0; k0 < 1024; k0 += 64) {
    __syncthreads();
    for (int i = 0; i < 4; ++i) {
      int s = w * 4 + i;
      int row = s * 8 + (l >> 3), colb = (l & 7) * 8;
      gld16(A + (size_t)(mBase + row) * 1024 + k0 + colb, As + s * 512);
      gld16(W + (size_t)(nBase + row) * 1024 + k0 + colb, Bs + s * 512);
    }
    __syncthreads();
    for (int kk = 0; kk < 2; ++kk) {
      bf16x8 af[4], bfm[4];
      for (int mr = 0; mr < 4; ++mr)
        af[mr] = *(const bf16x8*)&As[(wm * 64 + mr * 16 + lo) * 64 + kk * 32 + hi * 8];
      for (int nr = 0; nr < 4; ++nr)
        bfm[nr] = *(const bf16x8*)&Bs[(wn * 64 + nr * 16 + lo) * 64 + kk * 32 + hi * 8];
      for (int mr = 0; mr < 4; ++mr)
        for (int nr = 0; nr < 4; ++nr)
          acc[mr][nr] = __builtin_amdgcn_mfma_f32_16x16x32_bf16(
              af[mr], bfm[nr], acc[mr][nr], 0, 0, 0);
    }
  }

  if (blockIdx.z == 2) {
    for (int nr = 0; nr < 4; ++nr) {
      int col = nBase + wn * 64 + nr * 16 + lo;
      float bv = bias[col];
      int hh = col >> 6, dd = col & 63;
      for (int mr = 0; mr < 4; ++mr) {
        int rbase = mBase + wm * 64 + mr * 16 + hi * 4;
        int bb = rbase >> 11, ss = rbase & 2047;
        unsigned long long o = 0;
        for (int i = 0; i < 4; ++i)
          o |= (unsigned long long)f2bf(acc[mr][nr][i] + bv) << (16 * i);
        *(unsigned long long*)(C +
            ((size_t)((bb * H_NUM + hh) * 64 + dd) * S_LEN + ss)) = o;
      }
    }
  } else {
    for (int nr = 0; nr < 4; ++nr) {
      int col = nBase + wn * 64 + nr * 16 + lo;
      float bv = bias[col];
      for (int mr = 0; mr < 4; ++mr) {
        int rbase = mBase + wm * 64 + mr * 16 + hi * 4;
        for (int i = 0; i < 4; ++i)
          C[(size_t)(rbase + i) * 1024 + col] = f2bf(acc[mr][nr][i] + bv);
      }
    }
  }
}

// ---------------------------------------------------------------------------
// Output projection (unchanged, R3/R4/R6/R7-verified)
// ---------------------------------------------------------------------------
__global__ __launch_bounds__(256) void gemm_proj(
    const unsigned short* __restrict__ A, const float* __restrict__ W,
    const float* __restrict__ bias, float* __restrict__ C) {
  __shared__ __align__(16) unsigned short As[128][40];
  __shared__ __align__(16) unsigned short Bs[128][40];

  const int tid = threadIdx.x;
  const int l = tid & 63;
  const int w = tid >> 6;
  const int wm = w >> 1, wn = w & 1;
  const int lo = l & 15, hi = l >> 4;

  const int mBase = blockIdx.y * 128;
  const int nBase = blockIdx.x * 128;

  f32x4 acc[4][4];
  for (int mr = 0; mr < 4; ++mr)
    for (int nr = 0; nr < 4; ++nr) acc[mr][nr] = (f32x4){0.f, 0.f, 0.f, 0.f};

  for (int k0 = 0; k0 < 1024; k0 += 32) {
    __syncthreads();
    for (int it = 0; it < 2; ++it) {
      int c = tid + it * 256;
      int r = c >> 2, cc = (c & 3) * 8;
      *(int4*)&As[r][cc] = *(const int4*)(A + (size_t)(mBase + r) * 1024 + k0 + cc);
      const float* wp = W + (size_t)(nBase + r) * 1024 + k0 + cc;
      *(bf16x8*)&Bs[r][cc] = cvt8(((const float4*)wp)[0], ((const float4*)wp)[1]);
    }
    __syncthreads();
    bf16x8 af[4], bfm[4];
    for (int mr = 0; mr < 4; ++mr)
      af[mr] = *(const bf16x8*)&As[wm * 64 + mr * 16 + lo][hi * 8];
    for (int nr = 0; nr < 4; ++nr)
      bfm[nr] = *(const bf16x8*)&Bs[wn * 64 + nr * 16 + lo][hi * 8];
    for (int mr = 0; mr < 4; ++mr)
      for (int nr = 0; nr < 4; ++nr)
        acc[mr][nr] = __builtin_amdgcn_mfma_f32_16x16x32_bf16(
            af[mr], bfm[nr], acc[mr][nr], 0, 0, 0);
  }

  for (int nr = 0; nr < 4; ++nr) {
    int col = nBase + wn * 64 + nr * 16 + lo;
    float bv = bias[col];
    for (int mr = 0; mr < 4; ++mr) {
      int rbase = mBase + wm * 64 + mr * 16 + hi * 4;
      for (int i = 0; i < 4; ++i)
        C[(size_t)(rbase + i) * 1024 + col] = acc[mr][nr][i] + bv;
    }
  }
}

// ---------------------------------------------------------------------------
// Fused attention per (b, h, 64 q-rows); 4 waves x 16 q-rows, KBLK=64.
// Double-buffered LDS + async reg-prefetch (T14): ONE barrier per tile.
// P is per-wave (rows w*16..w*16+15): written, PV-read, and blitted by the
// owning wave only -> no extra barrier.  P stored bf16.
// ---------------------------------------------------------------------------
__global__ __launch_bounds__(256) void attn_kernel(
    const unsigned short* __restrict__ qb, const unsigned short* __restrict__ kb,
    const unsigned short* __restrict__ vT, const int* __restrict__ mask,
    float* __restrict__ attn, unsigned short* __restrict__ ctx) {
  // bijective XCD swizzle (1024 % 8 == 0): blocks sharing (b,h) on one XCD
  const int bid = blockIdx.x;
  const int wid = (bid & 7) * 128 + (bid >> 3);
  const int q0 = (wid & 31) * 64;
  const int h  = (wid >> 5) & 15;
  const int b  = wid >> 9;

  const int tid = threadIdx.x, l = tid & 63, w = tid >> 6;
  const int lo = l & 15, hi = l >> 4;

  __shared__ __align__(16) unsigned short k_lds[2][64][72];
  __shared__ __align__(16) unsigned short vt_lds[2][64][72];
  __shared__ __align__(16) unsigned short p_lds[64][72];

  // staging geometry: per thread 2 int4 chunks at rows r0, r0+32
  const int r0 = tid >> 3, cc0 = (tid & 7) * 8;

  // Q fragments for this wave's 16 q-rows (depth 64 -> 2 frags)
  bf16x8 qa[2];
  {
    const size_t qrow = (size_t)(b * S_LEN + q0 + w * 16 + lo) * D_DIM + h * 64;
    qa[0] = *(const bf16x8*)(qb + qrow + hi * 8);
    qa[1] = *(const bf16x8*)(qb + qrow + 32 + hi * 8);
  }

  const size_t kvbase = (size_t)b * S_LEN * D_DIM + h * 64;
  const unsigned short* vTh = vT + (size_t)((b * H_NUM + h) * 64) * S_LEN;
  const int* maskb = mask + b * S_LEN;

  int4 kreg[2], vreg[2];
#define LOAD_K(t) do { int _k0 = (t) * 64; \
    kreg[0] = *(const int4*)(kb + kvbase + (size_t)(_k0 + r0) * D_DIM + cc0); \
    kreg[1] = *(const int4*)(kb + kvbase + (size_t)(_k0 + r0 + 32) * D_DIM + cc0); } while (0)
#define LOAD_V(t) do { int _k0 = (t) * 64; \
    vreg[0] = *(const int4*)(vTh + (size_t)r0 * S_LEN + _k0 + cc0); \
    vreg[1] = *(const int4*)(vTh + (size_t)(r0 + 32) * S_LEN + _k0 + cc0); } while (0)
#define WRITE_K(bf) do { \
    *(int4*)&k_lds[bf][r0][cc0] = kreg[0]; \
    *(int4*)&k_lds[bf][r0 + 32][cc0] = kreg[1]; } while (0)
#define WRITE_V(bf) do { \
    *(int4*)&vt_lds[bf][r0][cc0] = vreg[0]; \
    *(int4*)&vt_lds[bf][r0 + 32][cc0] = vreg[1]; } while (0)

  // ---- phase 1: rowsums (K only, dbuf, 1 barrier/iter) ----
  float rsum[4] = {0.f, 0.f, 0.f, 0.f};
  LOAD_K(0); WRITE_K(0);
  LOAD_K(1);
  for (int kt = 0; kt < 32; ++kt) {
    __syncthreads();                 // buf[kt&1] staged for all; prev readers done
    WRITE_K((kt + 1) & 1);           // tile kt+1 (prefetched) -> other buffer
    int tn = kt + 2 < 32 ? kt + 2 : 31;
    LOAD_K(tn);                      // issue early; consumed next iter
    const int cur = kt & 1;
    const int key0 = kt * 64;
    f32x4 acc[4];
    for (int nr = 0; nr < 4; ++nr) acc[nr] = (f32x4){0.f, 0.f, 0.f, 0.f};
#pragma unroll
    for (int kk = 0; kk < 2; ++kk)
#pragma unroll
      for (int nr = 0; nr < 4; ++nr) {
        bf16x8 kf = *(const bf16x8*)&k_lds[cur][nr * 16 + lo][kk * 32 + hi * 8];
        acc[nr] = __builtin_amdgcn_mfma_f32_16x16x32_bf16(qa[kk], kf, acc[nr], 0, 0, 0);
      }
    for (int nr = 0; nr < 4; ++nr) {
      float ma = maskb[key0 + nr * 16 + lo] ? -1e9f : 0.f;
      for (int i = 0; i < 4; ++i)
        rsum[i] += __expf(acc[nr][i] * 0.125f + ma);
    }
  }
  for (int m = 1; m < 16; m <<= 1)
    for (int i = 0; i < 4; ++i) rsum[i] += __shfl_xor(rsum[i], m);
  float inv[4];
  for (int i = 0; i < 4; ++i) inv[i] = 1.0f / rsum[i];

  // ---- phase 2: recompute QK^T, write attn, fused PV (dbuf, 1 barrier/iter) ----
  f32x4 ctxacc[4];
  for (int dc = 0; dc < 4; ++dc) ctxacc[dc] = (f32x4){0.f, 0.f, 0.f, 0.f};
  const size_t attnbase = (size_t)(b * H_NUM + h) * S_LEN * S_LEN;

  LOAD_K(0); LOAD_V(0);
  WRITE_K(0); WRITE_V(0);            // safe: phase-1 stragglers only read buf[1]
  LOAD_K(1); LOAD_V(1);
  for (int kt = 0; kt < 32; ++kt) {
    __syncthreads();
    WRITE_K((kt + 1) & 1); WRITE_V((kt + 1) & 1);
    int tn = kt + 2 < 32 ? kt + 2 : 31;
    LOAD_K(tn); LOAD_V(tn);
    const int cur = kt & 1;
    const int key0 = kt * 64;

    f32x4 acc[4];
    for (int nr = 0; nr < 4; ++nr) acc[nr] = (f32x4){0.f, 0.f, 0.f, 0.f};
#pragma unroll
    for (int kk = 0; kk < 2; ++kk)
#pragma unroll
      for (int nr = 0; nr < 4; ++nr) {
        bf16x8 kf = *(const bf16x8*)&k_lds[cur][nr * 16 + lo][kk * 32 + hi * 8];
        acc[nr] = __builtin_amdgcn_mfma_f32_16x16x32_bf16(qa[kk], kf, acc[nr], 0, 0, 0);
      }
    for (int nr = 0; nr < 4; ++nr) {
      float ma = maskb[key0 + nr * 16 + lo] ? -1e9f : 0.f;
      for (int i = 0; i < 4; ++i) {
        float p = __expf(acc[nr][i] * 0.125f + ma) * inv[i];
        p_lds[w * 16 + hi * 4 + i][nr * 16 + lo] = f2bf(p);  // own wave's rows
      }
    }
    // same-wave p_lds write->read; lgkmcnt ordering is compiler-enforced
    bf16x8 pa[2];
    for (int kk = 0; kk < 2; ++kk)
      pa[kk] = *(const bf16x8*)&p_lds[w * 16 + lo][kk * 32 + hi * 8];
#pragma unroll
    for (int kk = 0; kk < 2; ++kk)
#pragma unroll
      for (int dc = 0; dc < 4; ++dc) {
        bf16x8 vf = *(const bf16x8*)&vt_lds[cur][dc * 16 + lo][kk * 32 + hi * 8];
        ctxacc[dc] = __builtin_amdgcn_mfma_f32_16x16x32_bf16(
            pa[kk], vf, ctxacc[dc], 0, 0, 0);
      }

    // attn blit: per-wave own 16 rows, bf16 -> f32, 256B segments
#pragma unroll
    for (int it = 0; it < 4; ++it) {
      int row = w * 16 + it * 4 + hi;
      int2 pk = *(const int2*)&p_lds[row][lo * 4];
      union { unsigned u; float f; } e0, e1, e2, e3;
      e0.u = (unsigned)pk.x << 16; e1.u = pk.x & 0xffff0000u;
      e2.u = (unsigned)pk.y << 16; e3.u = pk.y & 0xffff0000u;
      *(float4*)(attn + attnbase + (size_t)(q0 + row) * S_LEN + key0 + lo * 4) =
          (float4){e0.f, e1.f, e2.f, e3.f};
    }
  }

  // ctx epilogue: [B*S, D] bf16 with head offset
  for (int dc = 0; dc < 4; ++dc) {
    int col = h * 64 + dc * 16 + lo;
    for (int i = 0; i < 4; ++i) {
      int row = q0 + w * 16 + hi * 4 + i;
      ctx[(size_t)(b * S_LEN + row) * D_DIM + col] = f2bf(ctxacc[dc][i]);
    }
  }
#undef LOAD_K
#undef LOAD_V
#undef WRITE_K
#undef WRITE_V
}

// ---------------------------------------------------------------------------
// Host launch
// ---------------------------------------------------------------------------
extern "C" void kernel_launch(void* const* d_in, const int* in_sizes, int n_in,
                              void* d_out, int out_size, void* d_ws, size_t ws_size,
                              hipStream_t stream) {
  const float* x    = (const float*)d_in[0];
  const int*   mask = (const int*)d_in[1];
  const float* wq   = (const float*)d_in[2];
  const float* bq   = (const float*)d_in[3];
  const float* wk   = (const float*)d_in[4];
  const float* bk   = (const float*)d_in[5];
  const float* wv   = (const float*)d_in[6];
  const float* bv   = (const float*)d_in[7];
  const float* wd   = (const float*)d_in[8];
  const float* bd   = (const float*)d_in[9];

  float* out  = (float*)d_out;
  float* attn = out + (size_t)M_ROWS * D_DIM;   // +4,194,304 f32

  // transient bf16 scratch in the (not-yet-written) attn region;
  // fully consumed by gemm_qkv before attn_kernel overwrites it
  unsigned short* xb  = (unsigned short*)attn;
  unsigned short* wqb = xb + 4194304;
  unsigned short* wkb = xb + 5242880;
  unsigned short* wvb = xb + 6291456;   // ends at 14.7 MB << 537 MB

  // ws (bf16): 4 x 4,194,304 = 32 MiB
  unsigned short* ws   = (unsigned short*)d_ws;
  unsigned short* qb   = ws;
  unsigned short* kbuf = ws + 4194304;
  unsigned short* vTb  = ws + 8388608;    // vT[b][h][d][s]
  unsigned short* ctxb = ws + 12582912;

  cast_f32_bf16<<<4096, 256, 0, stream>>>(x,  xb,  1048576);
  cast_f32_bf16<<<1024, 256, 0, stream>>>(wq, wqb, 262144);
  cast_f32_bf16<<<1024, 256, 0, stream>>>(wk, wkb, 262144);
  cast_f32_bf16<<<1024, 256, 0, stream>>>(wv, wvb, 262144);

  gemm_qkv<<<dim3(8, 32, 3), 256, 0, stream>>>(
      xb, wqb, wkb, wvb, bq, bk, bv, qb, kbuf, vTb);

  attn_kernel<<<1024, 256, 0, stream>>>(qb, kbuf, vTb, mask, attn, ctxb);

  gemm_proj<<<dim3(8, 32), 256, 0, stream>>>(ctxb, wd, bd, out);
}

// Round 9
// 384.400 us; speedup vs baseline: 1.1009x; 1.1009x over previous
//
#include <hip/hip_runtime.h>

// ---------------------------------------------------------------------------
// MultiHeadAttention forward: B=2, S=2048, D=1024, H=16, depth=64
// d_out (f32): out [B,S,D] (4,194,304) ++ attn [B,H,S,S] (134,217,728)
// d_ws: q, k, vT, ctx bf16 = 4 x 8 MiB = 32 MiB.
// Transient scratch: bf16 x/w in attn region; inv rowsums in out region.
// ---------------------------------------------------------------------------

#define S_LEN 2048
#define D_DIM 1024
#define H_NUM 16
#define M_ROWS 4096   // B*S

typedef __attribute__((ext_vector_type(8))) short bf16x8;
typedef __attribute__((ext_vector_type(4))) float f32x4;

static __device__ __forceinline__ unsigned short f2bf(float f) {
  union { float f; unsigned u; } v; v.f = f;
  unsigned r = (v.u + 0x7FFFu + ((v.u >> 16) & 1u)) >> 16;  // RNE
  return (unsigned short)r;
}

static __device__ __forceinline__ bf16x8 cvt8(float4 a, float4 b) {
  bf16x8 r;
  r[0] = (short)f2bf(a.x); r[1] = (short)f2bf(a.y);
  r[2] = (short)f2bf(a.z); r[3] = (short)f2bf(a.w);
  r[4] = (short)f2bf(b.x); r[5] = (short)f2bf(b.y);
  r[6] = (short)f2bf(b.z); r[7] = (short)f2bf(b.w);
  return r;
}

static __device__ __forceinline__ void gld16(const void* g, void* s) {
  __builtin_amdgcn_global_load_lds(
      (const __attribute__((address_space(1))) unsigned int*)g,
      (__attribute__((address_space(3))) unsigned int*)s, 16, 0, 0);
}

// ---------------------------------------------------------------------------
__global__ __launch_bounds__(256) void cast_f32_bf16(
    const float* __restrict__ src, unsigned short* __restrict__ dst, int n4) {
  int i = blockIdx.x * 256 + threadIdx.x;
  if (i >= n4) return;
  float4 v = ((const float4*)src)[i];
  unsigned long long o =
      (unsigned long long)f2bf(v.x) |
      ((unsigned long long)f2bf(v.y) << 16) |
      ((unsigned long long)f2bf(v.z) << 32) |
      ((unsigned long long)f2bf(v.w) << 48);
  ((unsigned long long*)dst)[i] = o;
}

// ---------------------------------------------------------------------------
// m97-structure GEMM: C bf16 = A @ W^T + bias.  blockIdx.z selects q/k/v.
// z==2 (V) writes the result TRANSPOSED per head: vT[b][h][d][s].
// (unchanged, R6/R7/R8-verified)
// ---------------------------------------------------------------------------
__global__ __launch_bounds__(256) void gemm_qkv(
    const unsigned short* __restrict__ A,
    const unsigned short* __restrict__ W0, const unsigned short* __restrict__ W1,
    const unsigned short* __restrict__ W2,
    const float* __restrict__ b0, const float* __restrict__ b1,
    const float* __restrict__ b2,
    unsigned short* __restrict__ C0, unsigned short* __restrict__ C1,
    unsigned short* __restrict__ C2) {
  const unsigned short* W = W0; const float* bias = b0; unsigned short* C = C0;
  if (blockIdx.z == 1) { W = W1; bias = b1; C = C1; }
  else if (blockIdx.z == 2) { W = W2; bias = b2; C = C2; }

  __shared__ __align__(16) unsigned short As[128 * 64];
  __shared__ __align__(16) unsigned short Bs[128 * 64];

  const int tid = threadIdx.x;
  const int l = tid & 63;
  const int w = tid >> 6;
  const int wm = w >> 1, wn = w & 1;
  const int lo = l & 15, hi = l >> 4;

  const int mBase = blockIdx.y * 128;
  const int nBase = blockIdx.x * 128;

  f32x4 acc[4][4];
  for (int mr = 0; mr < 4; ++mr)
    for (int nr = 0; nr < 4; ++nr) acc[mr][nr] = (f32x4){0.f, 0.f, 0.f, 0.f};

  for (int k0 = 0; k0 < 1024; k0 += 64) {
    __syncthreads();
    for (int i = 0; i < 4; ++i) {
      int s = w * 4 + i;
      int row = s * 8 + (l >> 3), colb = (l & 7) * 8;
      gld16(A + (size_t)(mBase + row) * 1024 + k0 + colb, As + s * 512);
      gld16(W + (size_t)(nBase + row) * 1024 + k0 + colb, Bs + s * 512);
    }
    __syncthreads();
    for (int kk = 0; kk < 2; ++kk) {
      bf16x8 af[4], bfm[4];
      for (int mr = 0; mr < 4; ++mr)
        af[mr] = *(const bf16x8*)&As[(wm * 64 + mr * 16 + lo) * 64 + kk * 32 + hi * 8];
      for (int nr = 0; nr < 4; ++nr)
        bfm[nr] = *(const bf16x8*)&Bs[(wn * 64 + nr * 16 + lo) * 64 + kk * 32 + hi * 8];
      for (int mr = 0; mr < 4; ++mr)
        for (int nr = 0; nr < 4; ++nr)
          acc[mr][nr] = __builtin_amdgcn_mfma_f32_16x16x32_bf16(
              af[mr], bfm[nr], acc[mr][nr], 0, 0, 0);
    }
  }

  if (blockIdx.z == 2) {
    for (int nr = 0; nr < 4; ++nr) {
      int col = nBase + wn * 64 + nr * 16 + lo;
      float bv = bias[col];
      int hh = col >> 6, dd = col & 63;
      for (int mr = 0; mr < 4; ++mr) {
        int rbase = mBase + wm * 64 + mr * 16 + hi * 4;
        int bb = rbase >> 11, ss = rbase & 2047;
        unsigned long long o = 0;
        for (int i = 0; i < 4; ++i)
          o |= (unsigned long long)f2bf(acc[mr][nr][i] + bv) << (16 * i);
        *(unsigned long long*)(C +
            ((size_t)((bb * H_NUM + hh) * 64 + dd) * S_LEN + ss)) = o;
      }
    }
  } else {
    for (int nr = 0; nr < 4; ++nr) {
      int col = nBase + wn * 64 + nr * 16 + lo;
      float bv = bias[col];
      for (int mr = 0; mr < 4; ++mr) {
        int rbase = mBase + wm * 64 + mr * 16 + hi * 4;
        for (int i = 0; i < 4; ++i)
          C[(size_t)(rbase + i) * 1024 + col] = f2bf(acc[mr][nr][i] + bv);
      }
    }
  }
}

// ---------------------------------------------------------------------------
// Output projection (unchanged, R3..R8-verified)
// ---------------------------------------------------------------------------
__global__ __launch_bounds__(256) void gemm_proj(
    const unsigned short* __restrict__ A, const float* __restrict__ W,
    const float* __restrict__ bias, float* __restrict__ C) {
  __shared__ __align__(16) unsigned short As[128][40];
  __shared__ __align__(16) unsigned short Bs[128][40];

  const int tid = threadIdx.x;
  const int l = tid & 63;
  const int w = tid >> 6;
  const int wm = w >> 1, wn = w & 1;
  const int lo = l & 15, hi = l >> 4;

  const int mBase = blockIdx.y * 128;
  const int nBase = blockIdx.x * 128;

  f32x4 acc[4][4];
  for (int mr = 0; mr < 4; ++mr)
    for (int nr = 0; nr < 4; ++nr) acc[mr][nr] = (f32x4){0.f, 0.f, 0.f, 0.f};

  for (int k0 = 0; k0 < 1024; k0 += 32) {
    __syncthreads();
    for (int it = 0; it < 2; ++it) {
      int c = tid + it * 256;
      int r = c >> 2, cc = (c & 3) * 8;
      *(int4*)&As[r][cc] = *(const int4*)(A + (size_t)(mBase + r) * 1024 + k0 + cc);
      const float* wp = W + (size_t)(nBase + r) * 1024 + k0 + cc;
      *(bf16x8*)&Bs[r][cc] = cvt8(((const float4*)wp)[0], ((const float4*)wp)[1]);
    }
    __syncthreads();
    bf16x8 af[4], bfm[4];
    for (int mr = 0; mr < 4; ++mr)
      af[mr] = *(const bf16x8*)&As[wm * 64 + mr * 16 + lo][hi * 8];
    for (int nr = 0; nr < 4; ++nr)
      bfm[nr] = *(const bf16x8*)&Bs[wn * 64 + nr * 16 + lo][hi * 8];
    for (int mr = 0; mr < 4; ++mr)
      for (int nr = 0; nr < 4; ++nr)
        acc[mr][nr] = __builtin_amdgcn_mfma_f32_16x16x32_bf16(
            af[mr], bfm[nr], acc[mr][nr], 0, 0, 0);
  }

  for (int nr = 0; nr < 4; ++nr) {
    int col = nBase + wn * 64 + nr * 16 + lo;
    float bv = bias[col];
    for (int mr = 0; mr < 4; ++mr) {
      int rbase = mBase + wm * 64 + mr * 16 + hi * 4;
      for (int i = 0; i < 4; ++i)
        C[(size_t)(rbase + i) * 1024 + col] = acc[mr][nr][i] + bv;
    }
  }
}

// ---------------------------------------------------------------------------
// Rowsum kernel: inv[b][h][q] = 1 / sum_k exp(s).  K-only LDS (9.2 KB) ->
// high occupancy.  Math identical to the R7 phase-1 (verified).
// ---------------------------------------------------------------------------
__global__ __launch_bounds__(256) void rowsum_kernel(
    const unsigned short* __restrict__ qb, const unsigned short* __restrict__ kb,
    const int* __restrict__ mask, float* __restrict__ invb) {
  const int bid = blockIdx.x;
  const int wid = (bid & 7) * 128 + (bid >> 3);
  const int q0 = (wid & 31) * 64;
  const int h  = (wid >> 5) & 15;
  const int b  = wid >> 9;

  const int tid = threadIdx.x, l = tid & 63, w = tid >> 6;
  const int lo = l & 15, hi = l >> 4;

  __shared__ __align__(16) unsigned short k_lds[64][72];

  bf16x8 qa[2];
  {
    const size_t qrow = (size_t)(b * S_LEN + q0 + w * 16 + lo) * D_DIM + h * 64;
    qa[0] = *(const bf16x8*)(qb + qrow + hi * 8);
    qa[1] = *(const bf16x8*)(qb + qrow + 32 + hi * 8);
  }
  const size_t kvbase = (size_t)b * S_LEN * D_DIM + h * 64;
  const int* maskb = mask + b * S_LEN;

  float rsum[4] = {0.f, 0.f, 0.f, 0.f};
  for (int kt = 0; kt < 32; ++kt) {
    const int key0 = kt * 64;
    __syncthreads();
#pragma unroll
    for (int it = 0; it < 2; ++it) {
      int c = tid + it * 256;
      int r = c >> 3, cc = (c & 7) * 8;
      *(int4*)&k_lds[r][cc] =
          *(const int4*)(kb + kvbase + (size_t)(key0 + r) * D_DIM + cc);
    }
    __syncthreads();
    f32x4 acc[4];
    for (int nr = 0; nr < 4; ++nr) acc[nr] = (f32x4){0.f, 0.f, 0.f, 0.f};
#pragma unroll
    for (int kk = 0; kk < 2; ++kk)
#pragma unroll
      for (int nr = 0; nr < 4; ++nr) {
        bf16x8 kf = *(const bf16x8*)&k_lds[nr * 16 + lo][kk * 32 + hi * 8];
        acc[nr] = __builtin_amdgcn_mfma_f32_16x16x32_bf16(qa[kk], kf, acc[nr], 0, 0, 0);
      }
    for (int nr = 0; nr < 4; ++nr) {
      float ma = maskb[key0 + nr * 16 + lo] ? -1e9f : 0.f;
      for (int i = 0; i < 4; ++i)
        rsum[i] += __expf(acc[nr][i] * 0.125f + ma);
    }
  }
  for (int m = 1; m < 16; m <<= 1)
    for (int i = 0; i < 4; ++i) rsum[i] += __shfl_xor(rsum[i], m);
  if (lo == 0) {
    const int base = (b * H_NUM + h) * S_LEN + q0 + w * 16 + hi * 4;
    for (int i = 0; i < 4; ++i) invb[base + i] = 1.0f / rsum[i];
  }
}

// ---------------------------------------------------------------------------
// Attention pass: recompute QK^T, p = exp(s)*inv, write attn f32, fused PV.
// Single-buffer K/V staging (2 barriers/tile); P bf16 in wave-private LDS rows.
// LDS = 27.6 KB -> 5 blocks/CU.
// ---------------------------------------------------------------------------
__global__ __launch_bounds__(256) void attn_kernel(
    const unsigned short* __restrict__ qb, const unsigned short* __restrict__ kb,
    const unsigned short* __restrict__ vT, const int* __restrict__ mask,
    const float* __restrict__ invb, float* __restrict__ attn,
    unsigned short* __restrict__ ctx) {
  const int bid = blockIdx.x;
  const int wid = (bid & 7) * 128 + (bid >> 3);
  const int q0 = (wid & 31) * 64;
  const int h  = (wid >> 5) & 15;
  const int b  = wid >> 9;

  const int tid = threadIdx.x, l = tid & 63, w = tid >> 6;
  const int lo = l & 15, hi = l >> 4;

  __shared__ __align__(16) unsigned short k_lds[64][72];
  __shared__ __align__(16) unsigned short vt_lds[64][72];
  __shared__ __align__(16) unsigned short p_lds[64][72];

  bf16x8 qa[2];
  {
    const size_t qrow = (size_t)(b * S_LEN + q0 + w * 16 + lo) * D_DIM + h * 64;
    qa[0] = *(const bf16x8*)(qb + qrow + hi * 8);
    qa[1] = *(const bf16x8*)(qb + qrow + 32 + hi * 8);
  }
  const size_t kvbase = (size_t)b * S_LEN * D_DIM + h * 64;
  const unsigned short* vTh = vT + (size_t)((b * H_NUM + h) * 64) * S_LEN;
  const int* maskb = mask + b * S_LEN;

  float inv[4];
  {
    const int base = (b * H_NUM + h) * S_LEN + q0 + w * 16 + hi * 4;
    for (int i = 0; i < 4; ++i) inv[i] = invb[base + i];
  }

  f32x4 ctxacc[4];
  for (int dc = 0; dc < 4; ++dc) ctxacc[dc] = (f32x4){0.f, 0.f, 0.f, 0.f};
  const size_t attnbase = (size_t)(b * H_NUM + h) * S_LEN * S_LEN;

  for (int kt = 0; kt < 32; ++kt) {
    const int key0 = kt * 64;
    __syncthreads();   // prior iter's k/vt readers done
#pragma unroll
    for (int it = 0; it < 2; ++it) {
      int c = tid + it * 256;
      int r = c >> 3, cc = (c & 7) * 8;
      *(int4*)&k_lds[r][cc] =
          *(const int4*)(kb + kvbase + (size_t)(key0 + r) * D_DIM + cc);
      *(int4*)&vt_lds[r][cc] =
          *(const int4*)(vTh + (size_t)r * S_LEN + key0 + cc);
    }
    __syncthreads();
    f32x4 acc[4];
    for (int nr = 0; nr < 4; ++nr) acc[nr] = (f32x4){0.f, 0.f, 0.f, 0.f};
#pragma unroll
    for (int kk = 0; kk < 2; ++kk)
#pragma unroll
      for (int nr = 0; nr < 4; ++nr) {
        bf16x8 kf = *(const bf16x8*)&k_lds[nr * 16 + lo][kk * 32 + hi * 8];
        acc[nr] = __builtin_amdgcn_mfma_f32_16x16x32_bf16(qa[kk], kf, acc[nr], 0, 0, 0);
      }
    // p (bf16) into wave-private rows; same-wave write->read, no barrier
    for (int nr = 0; nr < 4; ++nr) {
      float ma = maskb[key0 + nr * 16 + lo] ? -1e9f : 0.f;
      for (int i = 0; i < 4; ++i) {
        float p = __expf(acc[nr][i] * 0.125f + ma) * inv[i];
        p_lds[w * 16 + hi * 4 + i][nr * 16 + lo] = f2bf(p);
      }
    }
    bf16x8 pa[2];
    for (int kk = 0; kk < 2; ++kk)
      pa[kk] = *(const bf16x8*)&p_lds[w * 16 + lo][kk * 32 + hi * 8];
#pragma unroll
    for (int kk = 0; kk < 2; ++kk)
#pragma unroll
      for (int dc = 0; dc < 4; ++dc) {
        bf16x8 vf = *(const bf16x8*)&vt_lds[dc * 16 + lo][kk * 32 + hi * 8];
        ctxacc[dc] = __builtin_amdgcn_mfma_f32_16x16x32_bf16(
            pa[kk], vf, ctxacc[dc], 0, 0, 0);
      }
    // attn blit: wave-own 16 rows, bf16 -> f32, 256B segments
#pragma unroll
    for (int it = 0; it < 4; ++it) {
      int row = w * 16 + it * 4 + hi;
      int2 pk = *(const int2*)&p_lds[row][lo * 4];
      union { unsigned u; float f; } e0, e1, e2, e3;
      e0.u = (unsigned)pk.x << 16; e1.u = pk.x & 0xffff0000u;
      e2.u = (unsigned)pk.y << 16; e3.u = pk.y & 0xffff0000u;
      *(float4*)(attn + attnbase + (size_t)(q0 + row) * S_LEN + key0 + lo * 4) =
          (float4){e0.f, e1.f, e2.f, e3.f};
    }
  }

  // ctx epilogue: [B*S, D] bf16 with head offset
  for (int dc = 0; dc < 4; ++dc) {
    int col = h * 64 + dc * 16 + lo;
    for (int i = 0; i < 4; ++i) {
      int row = q0 + w * 16 + hi * 4 + i;
      ctx[(size_t)(b * S_LEN + row) * D_DIM + col] = f2bf(ctxacc[dc][i]);
    }
  }
}

// ---------------------------------------------------------------------------
// Host launch
// ---------------------------------------------------------------------------
extern "C" void kernel_launch(void* const* d_in, const int* in_sizes, int n_in,
                              void* d_out, int out_size, void* d_ws, size_t ws_size,
                              hipStream_t stream) {
  const float* x    = (const float*)d_in[0];
  const int*   mask = (const int*)d_in[1];
  const float* wq   = (const float*)d_in[2];
  const float* bq   = (const float*)d_in[3];
  const float* wk   = (const float*)d_in[4];
  const float* bk   = (const float*)d_in[5];
  const float* wv   = (const float*)d_in[6];
  const float* bv   = (const float*)d_in[7];
  const float* wd   = (const float*)d_in[8];
  const float* bd   = (const float*)d_in[9];

  float* out  = (float*)d_out;
  float* attn = out + (size_t)M_ROWS * D_DIM;   // +4,194,304 f32

  // transient scratch #1: bf16 x/w in the (not-yet-written) attn region
  unsigned short* xb  = (unsigned short*)attn;
  unsigned short* wqb = xb + 4194304;
  unsigned short* wkb = xb + 5242880;
  unsigned short* wvb = xb + 6291456;   // ends at 14.7 MB << 537 MB

  // transient scratch #2: inv rowsums (256 KB) in the out region; consumed by
  // attn_kernel, then gemm_proj overwrites the whole out region (stream order)
  float* invb = out;

  // ws (bf16): 4 x 4,194,304 = 32 MiB
  unsigned short* ws   = (unsigned short*)d_ws;
  unsigned short* qb   = ws;
  unsigned short* kbuf = ws + 4194304;
  unsigned short* vTb  = ws + 8388608;    // vT[b][h][d][s]
  unsigned short* ctxb = ws + 12582912;

  cast_f32_bf16<<<4096, 256, 0, stream>>>(x,  xb,  1048576);
  cast_f32_bf16<<<1024, 256, 0, stream>>>(wq, wqb, 262144);
  cast_f32_bf16<<<1024, 256, 0, stream>>>(wk, wkb, 262144);
  cast_f32_bf16<<<1024, 256, 0, stream>>>(wv, wvb, 262144);

  gemm_qkv<<<dim3(8, 32, 3), 256, 0, stream>>>(
      xb, wqb, wkb, wvb, bq, bk, bv, qb, kbuf, vTb);

  rowsum_kernel<<<1024, 256, 0, stream>>>(qb, kbuf, mask, invb);

  attn_kernel<<<1024, 256, 0, stream>>>(qb, kbuf, vTb, mask, invb, attn, ctxb);

  gemm_proj<<<dim3(8, 32), 256, 0, stream>>>(ctxb, wd, bd, out);
}

// Round 10
// 343.400 us; speedup vs baseline: 1.2324x; 1.1194x over previous
//
#include <hip/hip_runtime.h>

// ---------------------------------------------------------------------------
// MultiHeadAttention forward: B=2, S=2048, D=1024, H=16, depth=64
// d_out (f32): out [B,S,D] (4,194,304) ++ attn [B,H,S,S] (134,217,728)
// d_ws: q, k, vT, ctx bf16 = 4 x 8 MiB = 32 MiB.
// 3 kernel launches: gemm_qkv3 -> attn_kernel -> gemm_proj.
// ---------------------------------------------------------------------------

#define S_LEN 2048
#define D_DIM 1024
#define H_NUM 16
#define M_ROWS 4096   // B*S

typedef __attribute__((ext_vector_type(8))) short bf16x8;
typedef __attribute__((ext_vector_type(4))) float f32x4;

static __device__ __forceinline__ unsigned short f2bf(float f) {
  union { float f; unsigned u; } v; v.f = f;
  unsigned r = (v.u + 0x7FFFu + ((v.u >> 16) & 1u)) >> 16;  // RNE
  return (unsigned short)r;
}

static __device__ __forceinline__ bf16x8 cvt8(float4 a, float4 b) {
  bf16x8 r;
  r[0] = (short)f2bf(a.x); r[1] = (short)f2bf(a.y);
  r[2] = (short)f2bf(a.z); r[3] = (short)f2bf(a.w);
  r[4] = (short)f2bf(b.x); r[5] = (short)f2bf(b.y);
  r[6] = (short)f2bf(b.z); r[7] = (short)f2bf(b.w);
  return r;
}

// ---------------------------------------------------------------------------
// QKV GEMM (R3-verified structure): C = x @ W^T + bias, f32 inputs converted
// to bf16 during LDS staging.  blockIdx.z selects q/k/v.  z==2 writes V
// transposed per head: vT[b][h][d][s] (R6-verified epilogue).
// ---------------------------------------------------------------------------
__global__ __launch_bounds__(256) void gemm_qkv3(
    const float* __restrict__ X,
    const float* __restrict__ W0, const float* __restrict__ W1,
    const float* __restrict__ W2,
    const float* __restrict__ b0, const float* __restrict__ b1,
    const float* __restrict__ b2,
    unsigned short* __restrict__ C0, unsigned short* __restrict__ C1,
    unsigned short* __restrict__ C2) {
  const float* W = W0; const float* bias = b0; unsigned short* C = C0;
  if (blockIdx.z == 1) { W = W1; bias = b1; C = C1; }
  else if (blockIdx.z == 2) { W = W2; bias = b2; C = C2; }

  __shared__ __align__(16) unsigned short As[128][40];
  __shared__ __align__(16) unsigned short Bs[128][40];

  const int tid = threadIdx.x;
  const int l = tid & 63;
  const int w = tid >> 6;
  const int wm = w >> 1, wn = w & 1;
  const int lo = l & 15, hi = l >> 4;

  const int mBase = blockIdx.y * 128;
  const int nBase = blockIdx.x * 128;

  f32x4 acc[4][4];
  for (int mr = 0; mr < 4; ++mr)
    for (int nr = 0; nr < 4; ++nr) acc[mr][nr] = (f32x4){0.f, 0.f, 0.f, 0.f};

  for (int k0 = 0; k0 < 1024; k0 += 32) {
    __syncthreads();
    for (int it = 0; it < 2; ++it) {
      int c = tid + it * 256;
      int r = c >> 2, cc = (c & 3) * 8;
      const float* ap = X + (size_t)(mBase + r) * 1024 + k0 + cc;
      *(bf16x8*)&As[r][cc] = cvt8(((const float4*)ap)[0], ((const float4*)ap)[1]);
      const float* wp = W + (size_t)(nBase + r) * 1024 + k0 + cc;
      *(bf16x8*)&Bs[r][cc] = cvt8(((const float4*)wp)[0], ((const float4*)wp)[1]);
    }
    __syncthreads();
    bf16x8 af[4], bfm[4];
    for (int mr = 0; mr < 4; ++mr)
      af[mr] = *(const bf16x8*)&As[wm * 64 + mr * 16 + lo][hi * 8];
    for (int nr = 0; nr < 4; ++nr)
      bfm[nr] = *(const bf16x8*)&Bs[wn * 64 + nr * 16 + lo][hi * 8];
    for (int mr = 0; mr < 4; ++mr)
      for (int nr = 0; nr < 4; ++nr)
        acc[mr][nr] = __builtin_amdgcn_mfma_f32_16x16x32_bf16(
            af[mr], bfm[nr], acc[mr][nr], 0, 0, 0);
  }

  if (blockIdx.z == 2) {
    // vT[b][h][d][s]: 4 consecutive s (C-rows) pack into one 8B store
    for (int nr = 0; nr < 4; ++nr) {
      int col = nBase + wn * 64 + nr * 16 + lo;
      float bv = bias[col];
      int hh = col >> 6, dd = col & 63;
      for (int mr = 0; mr < 4; ++mr) {
        int rbase = mBase + wm * 64 + mr * 16 + hi * 4;
        int bb = rbase >> 11, ss = rbase & 2047;
        unsigned long long o = 0;
        for (int i = 0; i < 4; ++i)
          o |= (unsigned long long)f2bf(acc[mr][nr][i] + bv) << (16 * i);
        *(unsigned long long*)(C +
            ((size_t)((bb * H_NUM + hh) * 64 + dd) * S_LEN + ss)) = o;
      }
    }
  } else {
    for (int nr = 0; nr < 4; ++nr) {
      int col = nBase + wn * 64 + nr * 16 + lo;
      float bv = bias[col];
      for (int mr = 0; mr < 4; ++mr) {
        int rbase = mBase + wm * 64 + mr * 16 + hi * 4;
        for (int i = 0; i < 4; ++i)
          C[(size_t)(rbase + i) * 1024 + col] = f2bf(acc[mr][nr][i] + bv);
      }
    }
  }
}

// ---------------------------------------------------------------------------
// Output projection (unchanged, R3..R9-verified)
// ---------------------------------------------------------------------------
__global__ __launch_bounds__(256) void gemm_proj(
    const unsigned short* __restrict__ A, const float* __restrict__ W,
    const float* __restrict__ bias, float* __restrict__ C) {
  __shared__ __align__(16) unsigned short As[128][40];
  __shared__ __align__(16) unsigned short Bs[128][40];

  const int tid = threadIdx.x;
  const int l = tid & 63;
  const int w = tid >> 6;
  const int wm = w >> 1, wn = w & 1;
  const int lo = l & 15, hi = l >> 4;

  const int mBase = blockIdx.y * 128;
  const int nBase = blockIdx.x * 128;

  f32x4 acc[4][4];
  for (int mr = 0; mr < 4; ++mr)
    for (int nr = 0; nr < 4; ++nr) acc[mr][nr] = (f32x4){0.f, 0.f, 0.f, 0.f};

  for (int k0 = 0; k0 < 1024; k0 += 32) {
    __syncthreads();
    for (int it = 0; it < 2; ++it) {
      int c = tid + it * 256;
      int r = c >> 2, cc = (c & 3) * 8;
      *(int4*)&As[r][cc] = *(const int4*)(A + (size_t)(mBase + r) * 1024 + k0 + cc);
      const float* wp = W + (size_t)(nBase + r) * 1024 + k0 + cc;
      *(bf16x8*)&Bs[r][cc] = cvt8(((const float4*)wp)[0], ((const float4*)wp)[1]);
    }
    __syncthreads();
    bf16x8 af[4], bfm[4];
    for (int mr = 0; mr < 4; ++mr)
      af[mr] = *(const bf16x8*)&As[wm * 64 + mr * 16 + lo][hi * 8];
    for (int nr = 0; nr < 4; ++nr)
      bfm[nr] = *(const bf16x8*)&Bs[wn * 64 + nr * 16 + lo][hi * 8];
    for (int mr = 0; mr < 4; ++mr)
      for (int nr = 0; nr < 4; ++nr)
        acc[mr][nr] = __builtin_amdgcn_mfma_f32_16x16x32_bf16(
            af[mr], bfm[nr], acc[mr][nr], 0, 0, 0);
  }

  for (int nr = 0; nr < 4; ++nr) {
    int col = nBase + wn * 64 + nr * 16 + lo;
    float bv = bias[col];
    for (int mr = 0; mr < 4; ++mr) {
      int rbase = mBase + wm * 64 + mr * 16 + hi * 4;
      for (int i = 0; i < 4; ++i)
        C[(size_t)(rbase + i) * 1024 + col] = acc[mr][nr][i] + bv;
    }
  }
}

// ---------------------------------------------------------------------------
// Fused attention per (b, h, 64 q-rows); 4 waves x 16 q-rows.
// Phase 1 (rowsums): KBLK=64, K-only staging, 2 barriers/tile.
// Phase 2: KBLK=32 (k reuses rows 0..31), vt/p tiles [64][40], P bf16
// wave-private (no 3rd barrier).  LDS 19.0 KB -> 8 blocks/CU.
// ---------------------------------------------------------------------------
__global__ __launch_bounds__(256) void attn_kernel(
    const unsigned short* __restrict__ qb, const unsigned short* __restrict__ kb,
    const unsigned short* __restrict__ vT, const int* __restrict__ mask,
    float* __restrict__ attn, unsigned short* __restrict__ ctx) {
  const int bid = blockIdx.x;
  const int q0 = (bid & 31) * 64;
  const int h  = (bid >> 5) & 15;
  const int b  = bid >> 9;

  const int tid = threadIdx.x, l = tid & 63, w = tid >> 6;
  const int lo = l & 15, hi = l >> 4;

  __shared__ __align__(16) unsigned short k_lds[64][72];   // ph1: 64 keys; ph2: rows 0..31
  __shared__ __align__(16) unsigned short vt_lds[64][40];  // 64 d x 32 keys
  __shared__ __align__(16) unsigned short p_lds[64][40];   // 64 q x 32 keys

  bf16x8 qa[2];
  {
    const size_t qrow = (size_t)(b * S_LEN + q0 + w * 16 + lo) * D_DIM + h * 64;
    qa[0] = *(const bf16x8*)(qb + qrow + hi * 8);
    qa[1] = *(const bf16x8*)(qb + qrow + 32 + hi * 8);
  }
  const size_t kvbase = (size_t)b * S_LEN * D_DIM + h * 64;
  const unsigned short* vTh = vT + (size_t)((b * H_NUM + h) * 64) * S_LEN;
  const int* maskb = mask + b * S_LEN;

  // ---- phase 1: rowsums (KBLK=64) ----
  float rsum[4] = {0.f, 0.f, 0.f, 0.f};
  for (int kt = 0; kt < 32; ++kt) {
    const int key0 = kt * 64;
    __syncthreads();
#pragma unroll
    for (int it = 0; it < 2; ++it) {
      int c = tid + it * 256;
      int r = c >> 3, cc = (c & 7) * 8;
      *(int4*)&k_lds[r][cc] =
          *(const int4*)(kb + kvbase + (size_t)(key0 + r) * D_DIM + cc);
    }
    __syncthreads();
    f32x4 acc[4];
    for (int nr = 0; nr < 4; ++nr) acc[nr] = (f32x4){0.f, 0.f, 0.f, 0.f};
#pragma unroll
    for (int kk = 0; kk < 2; ++kk)
#pragma unroll
      for (int nr = 0; nr < 4; ++nr) {
        bf16x8 kf = *(const bf16x8*)&k_lds[nr * 16 + lo][kk * 32 + hi * 8];
        acc[nr] = __builtin_amdgcn_mfma_f32_16x16x32_bf16(qa[kk], kf, acc[nr], 0, 0, 0);
      }
    for (int nr = 0; nr < 4; ++nr) {
      float ma = maskb[key0 + nr * 16 + lo] ? -1e9f : 0.f;
      for (int i = 0; i < 4; ++i)
        rsum[i] += __expf(acc[nr][i] * 0.125f + ma);
    }
  }
  for (int m = 1; m < 16; m <<= 1)
    for (int i = 0; i < 4; ++i) rsum[i] += __shfl_xor(rsum[i], m);
  float inv[4];
  for (int i = 0; i < 4; ++i) inv[i] = 1.0f / rsum[i];

  // ---- phase 2: recompute QK^T (KBLK=32), write attn, fused PV ----
  f32x4 ctxacc[4];
  for (int dc = 0; dc < 4; ++dc) ctxacc[dc] = (f32x4){0.f, 0.f, 0.f, 0.f};
  const size_t attnbase = (size_t)(b * H_NUM + h) * S_LEN * S_LEN;

  for (int kt = 0; kt < 64; ++kt) {
    const int key0 = kt * 32;
    __syncthreads();   // prior iter's k/vt readers done (and ph1 stragglers at kt=0)
    {
      // K: 32 rows x 64 cols
      int rK = tid >> 3, cK = (tid & 7) * 8;
      *(int4*)&k_lds[rK][cK] =
          *(const int4*)(kb + kvbase + (size_t)(key0 + rK) * D_DIM + cK);
      // vT: 64 rows (d) x 32 cols (keys)
      int rV = tid >> 2, cV = (tid & 3) * 8;
      *(int4*)&vt_lds[rV][cV] =
          *(const int4*)(vTh + (size_t)rV * S_LEN + key0 + cV);
    }
    __syncthreads();

    f32x4 acc[2];
    acc[0] = (f32x4){0.f, 0.f, 0.f, 0.f};
    acc[1] = (f32x4){0.f, 0.f, 0.f, 0.f};
#pragma unroll
    for (int kk = 0; kk < 2; ++kk)
#pragma unroll
      for (int nr = 0; nr < 2; ++nr) {
        bf16x8 kf = *(const bf16x8*)&k_lds[nr * 16 + lo][kk * 32 + hi * 8];
        acc[nr] = __builtin_amdgcn_mfma_f32_16x16x32_bf16(qa[kk], kf, acc[nr], 0, 0, 0);
      }
    // p (bf16) into wave-private rows; same-wave write->read, no barrier
#pragma unroll
    for (int nr = 0; nr < 2; ++nr) {
      float ma = maskb[key0 + nr * 16 + lo] ? -1e9f : 0.f;
      for (int i = 0; i < 4; ++i) {
        float p = __expf(acc[nr][i] * 0.125f + ma) * inv[i];
        p_lds[w * 16 + hi * 4 + i][nr * 16 + lo] = f2bf(p);
      }
    }
    bf16x8 pa = *(const bf16x8*)&p_lds[w * 16 + lo][hi * 8];
#pragma unroll
    for (int dc = 0; dc < 4; ++dc) {
      bf16x8 vf = *(const bf16x8*)&vt_lds[dc * 16 + lo][hi * 8];
      ctxacc[dc] = __builtin_amdgcn_mfma_f32_16x16x32_bf16(pa, vf, ctxacc[dc], 0, 0, 0);
    }
    // attn blit: wave-own 16 rows x 32 cols, bf16 -> f32, 128B row segments
#pragma unroll
    for (int it = 0; it < 2; ++it) {
      int row = w * 16 + it * 8 + (l >> 3);
      int colb = (l & 7) * 4;
      int2 pk = *(const int2*)&p_lds[row][colb];
      union { unsigned u; float f; } e0, e1, e2, e3;
      e0.u = (unsigned)pk.x << 16; e1.u = pk.x & 0xffff0000u;
      e2.u = (unsigned)pk.y << 16; e3.u = pk.y & 0xffff0000u;
      *(float4*)(attn + attnbase + (size_t)(q0 + row) * S_LEN + key0 + colb) =
          (float4){e0.f, e1.f, e2.f, e3.f};
    }
  }

  // ctx epilogue: [B*S, D] bf16 with head offset
  for (int dc = 0; dc < 4; ++dc) {
    int col = h * 64 + dc * 16 + lo;
    for (int i = 0; i < 4; ++i) {
      int row = q0 + w * 16 + hi * 4 + i;
      ctx[(size_t)(b * S_LEN + row) * D_DIM + col] = f2bf(ctxacc[dc][i]);
    }
  }
}

// ---------------------------------------------------------------------------
// Host launch
// ---------------------------------------------------------------------------
extern "C" void kernel_launch(void* const* d_in, const int* in_sizes, int n_in,
                              void* d_out, int out_size, void* d_ws, size_t ws_size,
                              hipStream_t stream) {
  const float* x    = (const float*)d_in[0];
  const int*   mask = (const int*)d_in[1];
  const float* wq   = (const float*)d_in[2];
  const float* bq   = (const float*)d_in[3];
  const float* wk   = (const float*)d_in[4];
  const float* bk   = (const float*)d_in[5];
  const float* wv   = (const float*)d_in[6];
  const float* bv   = (const float*)d_in[7];
  const float* wd   = (const float*)d_in[8];
  const float* bd   = (const float*)d_in[9];

  float* out  = (float*)d_out;
  float* attn = out + (size_t)M_ROWS * D_DIM;   // +4,194,304 f32

  // ws (bf16): 4 x 4,194,304 = 32 MiB
  unsigned short* ws   = (unsigned short*)d_ws;
  unsigned short* qb   = ws;
  unsigned short* kbuf = ws + 4194304;
  unsigned short* vTb  = ws + 8388608;    // vT[b][h][d][s]
  unsigned short* ctxb = ws + 12582912;

  gemm_qkv3<<<dim3(8, 32, 3), 256, 0, stream>>>(
      x, wq, wk, wv, bq, bk, bv, qb, kbuf, vTb);

  attn_kernel<<<1024, 256, 0, stream>>>(qb, kbuf, vTb, mask, attn, ctxb);

  gemm_proj<<<dim3(8, 32), 256, 0, stream>>>(ctxb, wd, bd, out);
}